// Round 3
// baseline (2696.927 us; speedup 1.0000x reference)
//
#include <hip/hip_runtime.h>

#define D 128          // D_IN == D_OUT == 128
#define GEMM_ROWS 64   // rows per block in the dense GEMM

// ---------------------------------------------------------------------------
// out[i][j] = bias[j]  (must re-init every call: harness poisons d_out once
// and does not re-poison between replays)
// ---------------------------------------------------------------------------
__global__ __launch_bounds__(256) void init_out_kernel(float* __restrict__ out,
                                                       const float* __restrict__ bias,
                                                       int total4) {
    int idx = blockIdx.x * blockDim.x + threadIdx.x;
    int stride = gridDim.x * blockDim.x;
    for (; idx < total4; idx += stride) {
        int j4 = idx & 31;                       // 128 cols = 32 float4
        float4 b = ((const float4*)bias)[j4];
        ((float4*)out)[idx] = b;
    }
}

// ---------------------------------------------------------------------------
// S = X @ W    (fp32 vector GEMM; no fp32 MFMA on CDNA4)
// W (128x128, 64KB) fully in LDS; 64-row X tile in LDS (stride 132 to keep
// LDS reads at <=2-way bank aliasing, which is free).
// Thread (cg=tid&15, rg=tid>>4) computes rows rg*4..+3, cols {4cg..4cg+3} and
// {64+4cg..+3}  -> 4x8 accumulator in VGPRs, 1.5 B LDS traffic per FMA.
// ---------------------------------------------------------------------------
__global__ __launch_bounds__(256) void gemm_kernel(const float* __restrict__ X,
                                                   const float* __restrict__ W,
                                                   float* __restrict__ S,
                                                   int n_rows) {
    __shared__ float Ws[D * D];              // 64 KB
    __shared__ float Xs[GEMM_ROWS * 132];    // 33 KB, padded stride

    const int tid  = threadIdx.x;
    const int row0 = blockIdx.x * GEMM_ROWS;

    // stage W: 4096 float4 / 256 threads = 16 each (coalesced)
    #pragma unroll
    for (int i = 0; i < 16; ++i) {
        int idx = tid + i * 256;
        ((float4*)Ws)[idx] = ((const float4*)W)[idx];
    }
    // stage X tile: 64x128 = 2048 float4 / 256 threads = 8 each
    #pragma unroll
    for (int i = 0; i < 8; ++i) {
        int idx = tid + i * 256;
        int r = idx >> 5, c4 = idx & 31;
        if (row0 + r < n_rows) {
            float4 v = ((const float4*)(X + (size_t)(row0 + r) * D))[c4];
            *((float4*)&Xs[r * 132 + c4 * 4]) = v;
        }
    }
    __syncthreads();

    const int cg = tid & 15, rg = tid >> 4;
    const int r0 = rg * 4;
    const int c0 = cg * 4;        // first col quad
    const int c1 = 64 + cg * 4;   // second col quad (2-way banks only)

    float acc[4][8];
    #pragma unroll
    for (int r = 0; r < 4; ++r)
        #pragma unroll
        for (int c = 0; c < 8; ++c) acc[r][c] = 0.f;

    #pragma unroll 4
    for (int k = 0; k < D; ++k) {
        float4 w0 = *((const float4*)&Ws[k * D + c0]);
        float4 w1 = *((const float4*)&Ws[k * D + c1]);
        #pragma unroll
        for (int r = 0; r < 4; ++r) {
            float x = Xs[(r0 + r) * 132 + k];
            acc[r][0] += x * w0.x; acc[r][1] += x * w0.y;
            acc[r][2] += x * w0.z; acc[r][3] += x * w0.w;
            acc[r][4] += x * w1.x; acc[r][5] += x * w1.y;
            acc[r][6] += x * w1.z; acc[r][7] += x * w1.w;
        }
    }

    #pragma unroll
    for (int r = 0; r < 4; ++r) {
        int row = row0 + r0 + r;
        if (row < n_rows) {
            float4 o0 = {acc[r][0], acc[r][1], acc[r][2], acc[r][3]};
            float4 o1 = {acc[r][4], acc[r][5], acc[r][6], acc[r][7]};
            ((float4*)(S + (size_t)row * D))[cg]      = o0;
            ((float4*)(S + (size_t)row * D))[16 + cg] = o1;
        }
    }
}

// ---------------------------------------------------------------------------
// SpMM scatter: one wave per edge. Lane l handles float2 at cols 2l..2l+1.
// Gather S[col] (512 B coalesced), scale by edge weight, hardware fp32
// atomics into out[row].
// ---------------------------------------------------------------------------
__global__ __launch_bounds__(256) void spmm_kernel(const float* __restrict__ S,
                                                   const int* __restrict__ erow,
                                                   const int* __restrict__ ecol,
                                                   const float* __restrict__ ew,
                                                   float* __restrict__ out,
                                                   int n_edges) {
    const int lane   = threadIdx.x & 63;
    const int wave   = blockIdx.x * (blockDim.x >> 6) + (threadIdx.x >> 6);
    const int nwaves = gridDim.x * (blockDim.x >> 6);

    for (int e = wave; e < n_edges; e += nwaves) {
        int   col = ecol[e];
        int   row = erow[e];
        float w   = ew[e];
        float2 s  = *(((const float2*)(S + (size_t)col * D)) + lane);
        float* op = out + (size_t)row * D + lane * 2;
        unsafeAtomicAdd(op,     w * s.x);   // global_atomic_add_f32, no return
        unsafeAtomicAdd(op + 1, w * s.y);
    }
}

extern "C" void kernel_launch(void* const* d_in, const int* in_sizes, int n_in,
                              void* d_out, int out_size, void* d_ws, size_t ws_size,
                              hipStream_t stream) {
    const float* X    = (const float*)d_in[0];
    const int*   erow = (const int*)  d_in[1];
    const int*   ecol = (const int*)  d_in[2];
    const float* ew   = (const float*)d_in[3];
    const float* W    = (const float*)d_in[4];
    const float* bias = (const float*)d_in[5];
    float* out = (float*)d_out;
    float* S   = (float*)d_ws;                 // 100000*128*4 = 51.2 MB scratch

    const int n_nodes = in_sizes[0] / D;
    const int n_edges = in_sizes[1];

    init_out_kernel<<<2048, 256, 0, stream>>>(out, bias, n_nodes * (D / 4));
    gemm_kernel<<<(n_nodes + GEMM_ROWS - 1) / GEMM_ROWS, 256, 0, stream>>>(X, W, S, n_nodes);
    spmm_kernel<<<2048, 256, 0, stream>>>(S, erow, ecol, ew, out, n_edges);
}

// Round 4
// 684.695 us; speedup vs baseline: 3.9389x; 3.9389x over previous
//
#include <hip/hip_runtime.h>

#define D 128          // D_IN == D_OUT == 128
#define GEMM_ROWS 64   // rows per block in the dense GEMM

// ---------------------------------------------------------------------------
// S = X @ W    (fp32 vector GEMM; no fp32 MFMA on CDNA4)
// W (128x128, 64KB) fully in LDS; 64-row X tile in LDS (stride 132).
// Thread (cg,rg) computes a 4x8 register tile.
// ---------------------------------------------------------------------------
__global__ __launch_bounds__(256) void gemm_kernel(const float* __restrict__ X,
                                                   const float* __restrict__ W,
                                                   float* __restrict__ S,
                                                   int n_rows) {
    __shared__ float Ws[D * D];              // 64 KB
    __shared__ float Xs[GEMM_ROWS * 132];    // 33 KB, padded stride

    const int tid  = threadIdx.x;
    const int row0 = blockIdx.x * GEMM_ROWS;

    #pragma unroll
    for (int i = 0; i < 16; ++i) {
        int idx = tid + i * 256;
        ((float4*)Ws)[idx] = ((const float4*)W)[idx];
    }
    #pragma unroll
    for (int i = 0; i < 8; ++i) {
        int idx = tid + i * 256;
        int r = idx >> 5, c4 = idx & 31;
        if (row0 + r < n_rows) {
            float4 v = ((const float4*)(X + (size_t)(row0 + r) * D))[c4];
            *((float4*)&Xs[r * 132 + c4 * 4]) = v;
        }
    }
    __syncthreads();

    const int cg = tid & 15, rg = tid >> 4;
    const int r0 = rg * 4;
    const int c0 = cg * 4;
    const int c1 = 64 + cg * 4;

    float acc[4][8];
    #pragma unroll
    for (int r = 0; r < 4; ++r)
        #pragma unroll
        for (int c = 0; c < 8; ++c) acc[r][c] = 0.f;

    #pragma unroll 4
    for (int k = 0; k < D; ++k) {
        float4 w0 = *((const float4*)&Ws[k * D + c0]);
        float4 w1 = *((const float4*)&Ws[k * D + c1]);
        #pragma unroll
        for (int r = 0; r < 4; ++r) {
            float x = Xs[(r0 + r) * 132 + k];
            acc[r][0] += x * w0.x; acc[r][1] += x * w0.y;
            acc[r][2] += x * w0.z; acc[r][3] += x * w0.w;
            acc[r][4] += x * w1.x; acc[r][5] += x * w1.y;
            acc[r][6] += x * w1.z; acc[r][7] += x * w1.w;
        }
    }

    #pragma unroll
    for (int r = 0; r < 4; ++r) {
        int row = row0 + r0 + r;
        if (row < n_rows) {
            float4 o0 = {acc[r][0], acc[r][1], acc[r][2], acc[r][3]};
            float4 o1 = {acc[r][4], acc[r][5], acc[r][6], acc[r][7]};
            ((float4*)(S + (size_t)row * D))[cg]      = o0;
            ((float4*)(S + (size_t)row * D))[16 + cg] = o1;
        }
    }
}

// ---------------------------------------------------------------------------
// CSR build: histogram -> 3-kernel exclusive scan -> scatter.
// `offs` buffer lifecycle per call: counts (hist) -> start[] (scan3)
//  -> end[] (scatter's atomic cursors land at start+deg).
// ---------------------------------------------------------------------------
__global__ __launch_bounds__(256) void hist_kernel(const int* __restrict__ erow,
                                                   int* __restrict__ offs, int n_edges) {
    int i = blockIdx.x * blockDim.x + threadIdx.x;
    int stride = gridDim.x * blockDim.x;
    for (; i < n_edges; i += stride)
        atomicAdd(&offs[erow[i]], 1);
}

// block b: sum of offs[b*256 .. b*256+255] -> bsum[b]
__global__ __launch_bounds__(256) void scan1_kernel(const int* __restrict__ offs,
                                                    int* __restrict__ bsum, int n) {
    int i = blockIdx.x * 256 + threadIdx.x;
    int v = (i < n) ? offs[i] : 0;
    #pragma unroll
    for (int d = 32; d; d >>= 1) v += __shfl_down(v, d, 64);
    __shared__ int ws[4];
    int lane = threadIdx.x & 63, w = threadIdx.x >> 6;
    if (lane == 0) ws[w] = v;
    __syncthreads();
    if (threadIdx.x == 0) bsum[blockIdx.x] = ws[0] + ws[1] + ws[2] + ws[3];
}

// single block: exclusive scan of bsum[0..nblk) in place (nblk <= 1024)
__global__ __launch_bounds__(1024) void scan2_kernel(int* __restrict__ bsum, int nblk) {
    __shared__ int s[1024];
    int tid = threadIdx.x;
    int v = (tid < nblk) ? bsum[tid] : 0;
    s[tid] = v;
    __syncthreads();
    for (int d = 1; d < 1024; d <<= 1) {
        int t = (tid >= d) ? s[tid - d] : 0;
        __syncthreads();
        s[tid] += t;
        __syncthreads();
    }
    if (tid < nblk) bsum[tid] = s[tid] - v;   // exclusive
}

// block b: exclusive scan of its 256 counts + bsum[b] -> offs[i] = start[i]
__global__ __launch_bounds__(256) void scan3_kernel(int* __restrict__ offs,
                                                    const int* __restrict__ bsum, int n) {
    int i = blockIdx.x * 256 + threadIdx.x;
    int v = (i < n) ? offs[i] : 0;
    int lane = threadIdx.x & 63, w = threadIdx.x >> 6;
    int x = v;
    #pragma unroll
    for (int d = 1; d < 64; d <<= 1) {
        int t = __shfl_up(x, d, 64);
        if (lane >= d) x += t;
    }
    __shared__ int ws[4];
    if (lane == 63) ws[w] = x;
    __syncthreads();
    int woff = bsum[blockIdx.x];
    for (int j = 0; j < w; ++j) woff += ws[j];
    if (i < n) offs[i] = x - v + woff;        // exclusive within block + offset
}

__global__ __launch_bounds__(256) void scatter_kernel(const int* __restrict__ erow,
                                                      const int* __restrict__ ecol,
                                                      const float* __restrict__ ew,
                                                      int* __restrict__ offs,
                                                      int2* __restrict__ sorted,
                                                      int n_edges) {
    int i = blockIdx.x * blockDim.x + threadIdx.x;
    int stride = gridDim.x * blockDim.x;
    for (; i < n_edges; i += stride) {
        int row = erow[i];
        int pos = atomicAdd(&offs[row], 1);
        int2 p;
        p.x = ecol[i];
        p.y = __float_as_int(ew[i]);
        sorted[pos] = p;
    }
}

// ---------------------------------------------------------------------------
// CSR SpMM: one wave per node. Lane l owns cols 2l..2l+1 (float2).
// Register accumulation (bias folded in), single coalesced write. No atomics.
// ---------------------------------------------------------------------------
__global__ __launch_bounds__(256) void spmm_csr_kernel(const float* __restrict__ S,
                                                       const int* __restrict__ offs_end,
                                                       const int2* __restrict__ sorted,
                                                       const float* __restrict__ bias,
                                                       float* __restrict__ out,
                                                       int n_nodes) {
    int node = blockIdx.x * 4 + (threadIdx.x >> 6);
    int lane = threadIdx.x & 63;
    if (node >= n_nodes) return;
    int end   = offs_end[node];
    int start = node ? offs_end[node - 1] : 0;
    float2 b2 = ((const float2*)bias)[lane];
    float ax = b2.x, ay = b2.y;
    int e = start;
    for (; e + 1 < end; e += 2) {
        int2 p0 = sorted[e], p1 = sorted[e + 1];
        float2 s0 = ((const float2*)(S + (size_t)p0.x * D))[lane];
        float2 s1 = ((const float2*)(S + (size_t)p1.x * D))[lane];
        float w0 = __int_as_float(p0.y), w1 = __int_as_float(p1.y);
        ax += w0 * s0.x + w1 * s1.x;
        ay += w0 * s0.y + w1 * s1.y;
    }
    if (e < end) {
        int2 p = sorted[e];
        float2 s = ((const float2*)(S + (size_t)p.x * D))[lane];
        float w = __int_as_float(p.y);
        ax += w * s.x;
        ay += w * s.y;
    }
    float2 o; o.x = ax; o.y = ay;
    ((float2*)(out + (size_t)node * D))[lane] = o;
}

// ---------------------------------------------------------------------------
// Fallback path (only if ws_size can't hold the CSR buffers): atomics.
// ---------------------------------------------------------------------------
__global__ __launch_bounds__(256) void init_out_kernel(float* __restrict__ out,
                                                       const float* __restrict__ bias,
                                                       int total4) {
    int idx = blockIdx.x * blockDim.x + threadIdx.x;
    int stride = gridDim.x * blockDim.x;
    for (; idx < total4; idx += stride) {
        float4 b = ((const float4*)bias)[idx & 31];
        ((float4*)out)[idx] = b;
    }
}

__global__ __launch_bounds__(256) void spmm_atomic_kernel(const float* __restrict__ S,
                                                          const int* __restrict__ erow,
                                                          const int* __restrict__ ecol,
                                                          const float* __restrict__ ew,
                                                          float* __restrict__ out,
                                                          int n_edges) {
    const int lane   = threadIdx.x & 63;
    const int wave   = blockIdx.x * (blockDim.x >> 6) + (threadIdx.x >> 6);
    const int nwaves = gridDim.x * (blockDim.x >> 6);
    for (int e = wave; e < n_edges; e += nwaves) {
        int   col = ecol[e];
        int   row = erow[e];
        float w   = ew[e];
        float2 s  = *(((const float2*)(S + (size_t)col * D)) + lane);
        float* op = out + (size_t)row * D + lane * 2;
        unsafeAtomicAdd(op,     w * s.x);
        unsafeAtomicAdd(op + 1, w * s.y);
    }
}

extern "C" void kernel_launch(void* const* d_in, const int* in_sizes, int n_in,
                              void* d_out, int out_size, void* d_ws, size_t ws_size,
                              hipStream_t stream) {
    const float* X    = (const float*)d_in[0];
    const int*   erow = (const int*)  d_in[1];
    const int*   ecol = (const int*)  d_in[2];
    const float* ew   = (const float*)d_in[3];
    const float* W    = (const float*)d_in[4];
    const float* bias = (const float*)d_in[5];
    float* out = (float*)d_out;

    const int n_nodes = in_sizes[0] / D;
    const int n_edges = in_sizes[1];
    const int nblk    = (n_nodes + 255) / 256;   // scan blocks (<=1024)

    // workspace layout
    size_t s_bytes    = (size_t)n_nodes * D * sizeof(float);   // 51.2 MB
    size_t offs_bytes = (size_t)n_nodes * sizeof(int);         // 400 KB
    size_t bsum_bytes = 1024 * sizeof(int);
    size_t sort_bytes = (size_t)n_edges * sizeof(int2);        // 25.6 MB
    size_t need = s_bytes + offs_bytes + bsum_bytes + sort_bytes + 64;

    float* S = (float*)d_ws;

    gemm_kernel<<<(n_nodes + GEMM_ROWS - 1) / GEMM_ROWS, 256, 0, stream>>>(X, W, S, n_nodes);

    if (ws_size >= need && nblk <= 1024) {
        char* p = (char*)d_ws + s_bytes;
        int* offs = (int*)p;            p += offs_bytes;
        int* bsum = (int*)p;            p += bsum_bytes;
        p = (char*)(((uintptr_t)p + 15) & ~(uintptr_t)15);
        int2* sorted = (int2*)p;

        hipMemsetAsync(offs, 0, offs_bytes, stream);
        hist_kernel<<<1024, 256, 0, stream>>>(erow, offs, n_edges);
        scan1_kernel<<<nblk, 256, 0, stream>>>(offs, bsum, n_nodes);
        scan2_kernel<<<1, 1024, 0, stream>>>(bsum, nblk);
        scan3_kernel<<<nblk, 256, 0, stream>>>(offs, bsum, n_nodes);
        scatter_kernel<<<1024, 256, 0, stream>>>(erow, ecol, ew, offs, sorted, n_edges);
        spmm_csr_kernel<<<(n_nodes + 3) / 4, 256, 0, stream>>>(S, offs, sorted, bias,
                                                               out, n_nodes);
    } else {
        init_out_kernel<<<2048, 256, 0, stream>>>(out, bias, n_nodes * (D / 4));
        spmm_atomic_kernel<<<2048, 256, 0, stream>>>(S, erow, ecol, ew, out, n_edges);
    }
}